// Round 3
// baseline (253.291 us; speedup 1.0000x reference)
//
#include <hip/hip_runtime.h>
#include <hip/hip_bf16.h>
#include <math.h>

#define KSPLIT 16
#define KCHUNK 256
#define BJ 128
#define TSPLIT 4

// ---------------------------------------------------------------------------
// Split-K batched GEMV: part[ks][b][col] = sum_{k in chunk ks} x[b][k]*w[col][k]
// Three weight pointers so QKV fuses into one launch.
// x: [32][4096], w rows are length-4096, part: [KSPLIT][32][ncols]
// ---------------------------------------------------------------------------
__global__ __launch_bounds__(256) void gemv_part_kernel(
    const float* __restrict__ x,
    const float* __restrict__ w0,
    const float* __restrict__ w1,
    const float* __restrict__ w2,
    int jb1, int jb2,
    int off0, int off1, int off2,
    int ncols,
    float* __restrict__ part)
{
  __shared__ float xt[KCHUNK][32];  // transposed x chunk: [k][b]
  int jb = blockIdx.x, ks = blockIdx.y;
  int k0 = ks * KCHUNK;
  const float* w; int colOff, jbase;
  if (jb < jb1)      { w = w0; colOff = off0; jbase = jb * BJ; }
  else if (jb < jb2) { w = w1; colOff = off1; jbase = (jb - jb1) * BJ; }
  else               { w = w2; colOff = off2; jbase = (jb - jb2) * BJ; }
  int tid = threadIdx.x;
  {
    int b = tid & 31, kg = tid >> 5;
    const float* xr = x + (size_t)b * 4096 + k0 + kg * 32;
    #pragma unroll
    for (int i = 0; i < 8; i++) {
      float4 v = *(const float4*)(xr + i * 4);
      int k = kg * 32 + i * 4;
      xt[k + 0][b] = v.x; xt[k + 1][b] = v.y;
      xt[k + 2][b] = v.z; xt[k + 3][b] = v.w;
    }
  }
  __syncthreads();
  int bg = tid & 7, jg = tid >> 3;            // 8 b-groups x 32 j-groups
  const float* wb = w + (size_t)(jbase + jg * 4) * 4096 + k0;
  float acc[4][4] = {};
  #pragma unroll 4
  for (int k4 = 0; k4 < KCHUNK / 4; k4++) {
    float wr[4][4], xv[4][4];
    #pragma unroll
    for (int jj = 0; jj < 4; jj++) {
      float4 t = *(const float4*)(wb + (size_t)jj * 4096 + k4 * 4);
      wr[jj][0] = t.x; wr[jj][1] = t.y; wr[jj][2] = t.z; wr[jj][3] = t.w;
    }
    #pragma unroll
    for (int c = 0; c < 4; c++) {
      float4 t = *(const float4*)(&xt[k4 * 4 + c][bg * 4]);
      xv[c][0] = t.x; xv[c][1] = t.y; xv[c][2] = t.z; xv[c][3] = t.w;
    }
    #pragma unroll
    for (int jj = 0; jj < 4; jj++)
      #pragma unroll
      for (int bb = 0; bb < 4; bb++)
        acc[jj][bb] += wr[jj][0] * xv[0][bb] + wr[jj][1] * xv[1][bb]
                     + wr[jj][2] * xv[2][bb] + wr[jj][3] * xv[3][bb];
  }
  #pragma unroll
  for (int jj = 0; jj < 4; jj++) {
    int col = colOff + jbase + jg * 4 + jj;
    #pragma unroll
    for (int bb = 0; bb < 4; bb++) {
      int b_ = bg * 4 + bb;
      part[((size_t)ks * 32 + b_) * ncols + col] = acc[jj][bb];
    }
  }
}

// ---------------------------------------------------------------------------
// Reduce split-K partials; apply RoPE to cols < ropeEnd (pairs within heads).
// ---------------------------------------------------------------------------
__global__ __launch_bounds__(256) void reduce_rope_kernel(
    const float* __restrict__ part, int ncols,
    const float* __restrict__ cosv, const float* __restrict__ sinv,
    int ropeEnd, float* __restrict__ outb)
{
  int idx = blockIdx.x * 256 + threadIdx.x;   // pair index
  int np = ncols >> 1;
  int b = idx / np;
  int cp = idx - b * np;
  int col = cp * 2;
  float e = 0.f, o = 0.f;
  #pragma unroll
  for (int ks = 0; ks < KSPLIT; ks++) {
    float2 v = *(const float2*)(part + ((size_t)ks * 32 + b) * ncols + col);
    e += v.x; o += v.y;
  }
  if (col < ropeEnd) {
    int fi = (col & 127) >> 1;
    float c = cosv[fi], s = sinv[fi];
    float ne = e * c - o * s;
    float no = e * s + o * c;
    e = ne; o = no;
  }
  *(float2*)(outb + (size_t)b * ncols + col) = make_float2(e, o);
}

// ---------------------------------------------------------------------------
// Flash-decode attention. Grid: TSPLIT t-splits x 8 kv heads x 32 b = 1024.
// Per block: 4 q-heads, 512 t's; 4 waves x 128 t's (2 chunks of 64).
// QK phase: per-wave 8-row K subtiles staged global->reg->LDS (coalesced
// 2x512B per load instr), XOR-swizzled LDS tile, lane=(row,dgroup) partial
// dots + 3-level shfl reduce. Softmax/PV: lane-owns-t via sbuf.
// New token (t == start_pos) merged from RoPE'd k/v (cache not mutated).
// attn_part: [TSPLIT][32][8][4][130] = {m, l, o[128]}
// ---------------------------------------------------------------------------
__global__ __launch_bounds__(256, 4) void attn_kernel(
    const float* __restrict__ qkv,       // [32][6144]
    const float* __restrict__ cache_k,   // [32][2048][8][128]
    const float* __restrict__ cache_v,
    const int* __restrict__ spp,
    float* __restrict__ attn_part)
{
  __shared__ float ktile[4][1024];   // per-wave 8x128 K subtile (swizzled)
  __shared__ float q_sw[640];        // q: [dq16=0..31] stride 20 floats x {4h x 4f}
  __shared__ float sbuf[4][64][4];   // per-wave s (then p) per (t, head)
  __shared__ float kn_s[128], vn_s[128];

  int bid = blockIdx.x;
  int ts = bid & (TSPLIT - 1), h = (bid >> 2) & 7, b = bid >> 5;
  int sp = *spp;                              // 2047
  const float scale = 0.088388347648318447f;  // 1/sqrt(128)
  int tid = threadIdx.x;

  if (tid < 128) {                            // q -> padded/scaled LDS copy
    int dq16 = tid & 31, r = tid >> 5;
    float4 qv = *(const float4*)(qkv + (size_t)b * 6144 + (h * 4 + r) * 128 + dq16 * 4);
    qv.x *= scale; qv.y *= scale; qv.z *= scale; qv.w *= scale;
    *(float4*)(&q_sw[dq16 * 20 + r * 4]) = qv;
  } else {
    int t2 = tid - 128;
    kn_s[t2] = qkv[(size_t)b * 6144 + 4096 + h * 128 + t2];
    vn_s[t2] = qkv[(size_t)b * 6144 + 5120 + h * 128 + t2];
  }
  __syncthreads();

  int wave = tid >> 6, lane = tid & 63;
  int half = lane >> 5, dq = lane & 31;       // staging / PV decomposition
  int rl = lane >> 3, dg = lane & 7;          // QK compute decomposition
  float* kt = &ktile[wave][0];
  int base0 = ts * 512 + wave * 128;
  const float* Kb = cache_k + (size_t)b * 2048 * 1024 + h * 128;
  const float* Vb = cache_v + (size_t)b * 2048 * 1024 + h * 128;

  float m[4]    = {-INFINITY, -INFINITY, -INFINITY, -INFINITY};
  float lsum[4] = {0.f, 0.f, 0.f, 0.f};
  float o[4][4] = {};

  // fixed per-lane offsets
  const int wr_byte = (dq * 16);              // staging col (pre-swizzle)
  char* ktc = (char*)kt;

  for (int c = 0; c < 2; c++) {
    int tbase = base0 + c * 64;
    const float* src0 = Kb + (size_t)(tbase + half) * 1024 + dq * 4;

    auto LOADK = [&](float4* dst, int st) {
      #pragma unroll
      for (int j = 0; j < 4; j++)
        dst[j] = *(const float4*)(src0 + (size_t)(st * 8 + j * 2) * 1024);
    };
    auto WRITEK = [&](const float4* srcv) {
      #pragma unroll
      for (int j = 0; j < 4; j++) {
        int rw = j * 2 + half;
        *(float4*)(ktc + rw * 512 + (wr_byte ^ (rw << 4))) = srcv[j];
      }
    };
    auto COMPUTEK = [&](int st) {
      float sp4[4] = {0.f, 0.f, 0.f, 0.f};
      #pragma unroll
      for (int i = 0; i < 4; i++) {
        float4 kv = *(const float4*)(ktc + rl * 512 + ((dg * 64 + i * 16) ^ (rl << 4)));
        int qo = (dg * 4 + i) * 20;
        #pragma unroll
        for (int r = 0; r < 4; r++) {
          float4 qv = *(const float4*)(&q_sw[qo + r * 4]);
          sp4[r] += kv.x * qv.x + kv.y * qv.y + kv.z * qv.z + kv.w * qv.w;
        }
      }
      #pragma unroll
      for (int r = 0; r < 4; r++) {
        sp4[r] += __shfl_xor(sp4[r], 1);
        sp4[r] += __shfl_xor(sp4[r], 2);
        sp4[r] += __shfl_xor(sp4[r], 4);
      }
      if (dg == 0)
        *(float4*)(&sbuf[wave][st * 8 + rl][0]) =
            make_float4(sp4[0], sp4[1], sp4[2], sp4[3]);
    };

    // 8 subtiles of 8 rows, 2-deep register prefetch, wave-private (no barriers)
    float4 st_reg[2][4];
    LOADK(st_reg[0], 0);
    LOADK(st_reg[1], 1);
    #pragma unroll
    for (int st = 0; st < 8; st++) {
      WRITEK(st_reg[st & 1]);
      if (st + 2 < 8) LOADK(st_reg[st & 1], st + 2);
      COMPUTEK(st);
    }

    // ---- softmax bookkeeping: lane owns t = tbase + lane ----
    int t = tbase + lane;
    float4 sv = *(const float4*)(&sbuf[wave][lane][0]);
    float s4[4] = {sv.x, sv.y, sv.z, sv.w};
    if (t >= sp) { s4[0] = s4[1] = s4[2] = s4[3] = -INFINITY; }
    float pv[4];
    #pragma unroll
    for (int r = 0; r < 4; r++) {
      float cm = s4[r];
      #pragma unroll
      for (int off = 32; off >= 1; off >>= 1) cm = fmaxf(cm, __shfl_xor(cm, off));
      float nm = fmaxf(m[r], cm);
      float alpha, p;
      if (nm == -INFINITY) { alpha = 1.f; p = 0.f; }
      else {
        alpha = __expf(m[r] - nm);
        p = (s4[r] == -INFINITY) ? 0.f : __expf(s4[r] - nm);
      }
      m[r] = nm;
      lsum[r] = lsum[r] * alpha + p;
      #pragma unroll
      for (int j = 0; j < 4; j++) o[r][j] *= alpha;
      pv[r] = p;
    }
    *(float4*)(&sbuf[wave][lane][0]) = make_float4(pv[0], pv[1], pv[2], pv[3]);

    // ---- PV: half-wave owns t-parity, dq owns d-quad; 2x512B per instr ----
    #pragma unroll 8
    for (int tt = 0; tt < 32; tt++) {
      int tcur = tbase + tt * 2 + half;
      float4 vv = *(const float4*)(Vb + (size_t)tcur * 1024 + dq * 4);
      const float* pp = &sbuf[wave][tt * 2 + half][0];
      #pragma unroll
      for (int r = 0; r < 4; r++) {
        float p = pp[r];
        o[r][0] += p * vv.x; o[r][1] += p * vv.y;
        o[r][2] += p * vv.z; o[r][3] += p * vv.w;
      }
    }
  }

  // merge the new token (position sp) from RoPE'd k/v in the owning block
  if (wave == 0 && sp >= ts * 512 && sp < ts * 512 + 512) {
    float sNew[4];
    #pragma unroll
    for (int r = 0; r < 4; r++) {
      float4 qv4 = *(const float4*)(&q_sw[(lane >> 1) * 20 + r * 4]);
      float q0 = (lane & 1) ? qv4.z : qv4.x;
      float q1 = (lane & 1) ? qv4.w : qv4.y;
      float a = q0 * kn_s[lane * 2] + q1 * kn_s[lane * 2 + 1];
      #pragma unroll
      for (int off = 32; off >= 1; off >>= 1) a += __shfl_xor(a, off);
      sNew[r] = a;
    }
    #pragma unroll
    for (int r = 0; r < 4; r++) {
      float nm = fmaxf(m[r], sNew[r]);
      float alpha = (m[r] == -INFINITY) ? 0.f : __expf(m[r] - nm);
      float p = __expf(sNew[r] - nm);
      m[r] = nm;
      lsum[r] = lsum[r] * alpha + ((lane == 0) ? p : 0.f);
      float sel = (half == 0) ? p : 0.f;      // add new token once per d-quad
      #pragma unroll
      for (int j = 0; j < 4; j++)
        o[r][j] = o[r][j] * alpha + sel * vn_s[dq * 4 + j];
    }
  }

  // per-wave wrap-up: publish (m, l, o) into this wave's ktile slice
  // layout: [0..511]=o[4][128], [512..515]=m, [516..519]=l
  {
    float* comb = &ktile[wave][0];
    #pragma unroll
    for (int r = 0; r < 4; r++) {
      float L = lsum[r];
      #pragma unroll
      for (int off = 32; off >= 1; off >>= 1) L += __shfl_xor(L, off);
      #pragma unroll
      for (int j = 0; j < 4; j++) o[r][j] += __shfl_xor(o[r][j], 32);
      if (lane == 0) { comb[512 + r] = m[r]; comb[516 + r] = L; }
      if (half == 0) {
        #pragma unroll
        for (int j = 0; j < 4; j++) comb[r * 128 + dq * 4 + j] = o[r][j];
      }
    }
  }
  __syncthreads();
  // combine 4 waves; thread = (r, d-pair)
  {
    int r = tid >> 6, dp = tid & 63;
    float gm = fmaxf(fmaxf(ktile[0][512 + r], ktile[1][512 + r]),
                     fmaxf(ktile[2][512 + r], ktile[3][512 + r]));
    float L = 0.f, O0 = 0.f, O1 = 0.f;
    #pragma unroll
    for (int wv = 0; wv < 4; wv++) {
      float mm = ktile[wv][512 + r];
      float al = (mm == -INFINITY) ? 0.f : __expf(mm - gm);
      L  += ktile[wv][516 + r] * al;
      O0 += ktile[wv][r * 128 + dp * 2]     * al;
      O1 += ktile[wv][r * 128 + dp * 2 + 1] * al;
    }
    float* ap = attn_part + ((((size_t)ts * 32 + b) * 8 + h) * 4 + r) * 130;
    if (dp == 0) { ap[0] = gm; ap[1] = L; }
    ap[2 + dp * 2] = O0;
    ap[3 + dp * 2] = O1;
  }
}

// ---------------------------------------------------------------------------
// Combine the TSPLIT t-split partials and divide by l.
// ---------------------------------------------------------------------------
__global__ __launch_bounds__(256) void attn_combine_kernel(
    const float* __restrict__ attn_part, float* __restrict__ attn)
{
  int idx = blockIdx.x * 256 + threadIdx.x;   // 131072 = 32*8*4*128
  int d = idx & 127;
  int r = (idx >> 7) & 3;
  int h = (idx >> 9) & 7;
  int b = idx >> 12;
  float mv[TSPLIT], lv[TSPLIT], ov[TSPLIT];
  float gm = -INFINITY;
  #pragma unroll
  for (int ts = 0; ts < TSPLIT; ts++) {
    const float* ap = attn_part + (((size_t)(ts * 32 + b) * 8 + h) * 4 + r) * 130;
    mv[ts] = ap[0]; lv[ts] = ap[1]; ov[ts] = ap[2 + d];
    gm = fmaxf(gm, mv[ts]);
  }
  float L = 0.f, O = 0.f;
  #pragma unroll
  for (int ts = 0; ts < TSPLIT; ts++) {
    float al = (mv[ts] == -INFINITY) ? 0.f : __expf(mv[ts] - gm);
    L += lv[ts] * al;
    O += ov[ts] * al;
  }
  attn[idx] = O / L;                          // idx == b*4096 + (h*4+r)*128 + d
}

extern "C" void kernel_launch(void* const* d_in, const int* in_sizes, int n_in,
                              void* d_out, int out_size, void* d_ws, size_t ws_size,
                              hipStream_t stream)
{
  const float* x   = (const float*)d_in[0];
  const float* wq  = (const float*)d_in[1];
  const float* wk  = (const float*)d_in[2];
  const float* wv  = (const float*)d_in[3];
  const float* wo  = (const float*)d_in[4];
  const float* fc  = (const float*)d_in[5];
  const float* fs  = (const float*)d_in[6];
  const float* ck  = (const float*)d_in[7];
  const float* cv  = (const float*)d_in[8];
  const int*   spp = (const int*)d_in[9];
  float* out = (float*)d_out;

  float* ws = (float*)d_ws;
  float* qkv_part  = ws;                    // [16][32][6144] = 3145728 f
  float* out_part  = ws;                    // alias: disjoint lifetime
  float* qkvbuf    = ws + 3145728;          // [32][6144]     = 196608 f
  float* attn_part = qkvbuf + 196608;       // [4][32][8][4][130] = 532480 f
  float* attnbuf   = attn_part + 532480;    // [32][4096]     = 131072 f

  // QKV projections (fused, split-K)
  gemv_part_kernel<<<dim3(48, KSPLIT), 256, 0, stream>>>(
      x, wq, wk, wv, 32, 40, 0, 4096, 5120, 6144, qkv_part);
  // reduce + RoPE (q and k rotated, v passthrough)
  reduce_rope_kernel<<<384, 256, 0, stream>>>(qkv_part, 6144, fc, fs, 5120, qkvbuf);
  // attention over KV cache + new token
  attn_kernel<<<1024, 256, 0, stream>>>(qkvbuf, ck, cv, spp, attn_part);
  attn_combine_kernel<<<512, 256, 0, stream>>>(attn_part, attnbuf);
  // output projection (split-K)
  gemv_part_kernel<<<dim3(32, KSPLIT), 256, 0, stream>>>(
      attnbuf, wo, wo, wo, 32, 32, 0, 0, 0, 4096, out_part);
  reduce_rope_kernel<<<256, 256, 0, stream>>>(out_part, 4096, fc, fs, 0, out);
}

// Round 4
// 220.249 us; speedup vs baseline: 1.1500x; 1.1500x over previous
//
#include <hip/hip_runtime.h>
#include <hip/hip_bf16.h>
#include <math.h>

#define KSPLIT 16
#define KCHUNK 256
#define BJ 128
#define TSPLIT 2

// ---------------------------------------------------------------------------
// Split-K batched GEMV: part[ks][b][col] = sum_{k in chunk ks} x[b][k]*w[col][k]
// Three weight pointers so QKV fuses into one launch.
// x: [32][4096], w rows are length-4096, part: [KSPLIT][32][ncols]
// ---------------------------------------------------------------------------
__global__ __launch_bounds__(256) void gemv_part_kernel(
    const float* __restrict__ x,
    const float* __restrict__ w0,
    const float* __restrict__ w1,
    const float* __restrict__ w2,
    int jb1, int jb2,
    int off0, int off1, int off2,
    int ncols,
    float* __restrict__ part)
{
  __shared__ float xt[KCHUNK][32];  // transposed x chunk: [k][b]
  int jb = blockIdx.x, ks = blockIdx.y;
  int k0 = ks * KCHUNK;
  const float* w; int colOff, jbase;
  if (jb < jb1)      { w = w0; colOff = off0; jbase = jb * BJ; }
  else if (jb < jb2) { w = w1; colOff = off1; jbase = (jb - jb1) * BJ; }
  else               { w = w2; colOff = off2; jbase = (jb - jb2) * BJ; }
  int tid = threadIdx.x;
  {
    int b = tid & 31, kg = tid >> 5;
    const float* xr = x + (size_t)b * 4096 + k0 + kg * 32;
    #pragma unroll
    for (int i = 0; i < 8; i++) {
      float4 v = *(const float4*)(xr + i * 4);
      int k = kg * 32 + i * 4;
      xt[k + 0][b] = v.x; xt[k + 1][b] = v.y;
      xt[k + 2][b] = v.z; xt[k + 3][b] = v.w;
    }
  }
  __syncthreads();
  int bg = tid & 7, jg = tid >> 3;            // 8 b-groups x 32 j-groups
  const float* wb = w + (size_t)(jbase + jg * 4) * 4096 + k0;
  float acc[4][4] = {};
  #pragma unroll 4
  for (int k4 = 0; k4 < KCHUNK / 4; k4++) {
    float wr[4][4], xv[4][4];
    #pragma unroll
    for (int jj = 0; jj < 4; jj++) {
      float4 t = *(const float4*)(wb + (size_t)jj * 4096 + k4 * 4);
      wr[jj][0] = t.x; wr[jj][1] = t.y; wr[jj][2] = t.z; wr[jj][3] = t.w;
    }
    #pragma unroll
    for (int c = 0; c < 4; c++) {
      float4 t = *(const float4*)(&xt[k4 * 4 + c][bg * 4]);
      xv[c][0] = t.x; xv[c][1] = t.y; xv[c][2] = t.z; xv[c][3] = t.w;
    }
    #pragma unroll
    for (int jj = 0; jj < 4; jj++)
      #pragma unroll
      for (int bb = 0; bb < 4; bb++)
        acc[jj][bb] += wr[jj][0] * xv[0][bb] + wr[jj][1] * xv[1][bb]
                     + wr[jj][2] * xv[2][bb] + wr[jj][3] * xv[3][bb];
  }
  #pragma unroll
  for (int jj = 0; jj < 4; jj++) {
    int col = colOff + jbase + jg * 4 + jj;
    #pragma unroll
    for (int bb = 0; bb < 4; bb++) {
      int b_ = bg * 4 + bb;
      part[((size_t)ks * 32 + b_) * ncols + col] = acc[jj][bb];
    }
  }
}

// ---------------------------------------------------------------------------
// Reduce split-K partials; apply RoPE to cols < ropeEnd (pairs within heads).
// ---------------------------------------------------------------------------
__global__ __launch_bounds__(256) void reduce_rope_kernel(
    const float* __restrict__ part, int ncols,
    const float* __restrict__ cosv, const float* __restrict__ sinv,
    int ropeEnd, float* __restrict__ outb)
{
  int idx = blockIdx.x * 256 + threadIdx.x;   // pair index
  int np = ncols >> 1;
  int b = idx / np;
  int cp = idx - b * np;
  int col = cp * 2;
  float e = 0.f, o = 0.f;
  #pragma unroll
  for (int ks = 0; ks < KSPLIT; ks++) {
    float2 v = *(const float2*)(part + ((size_t)ks * 32 + b) * ncols + col);
    e += v.x; o += v.y;
  }
  if (col < ropeEnd) {
    int fi = (col & 127) >> 1;
    float c = cosv[fi], s = sinv[fi];
    float ne = e * c - o * s;
    float no = e * s + o * c;
    e = ne; o = no;
  }
  *(float2*)(outb + (size_t)b * ncols + col) = make_float2(e, o);
}

// ---------------------------------------------------------------------------
// Flash-decode attention. Grid: TSPLIT x 8 kv heads x 32 b = 512 blocks.
// Per block: 4 q-heads, 1024 t's; 4 waves x 256 t's (4 chunks of 64).
// QK: lane=(row tl 0..7, colgroup dg 0..7); each wave-instr reads 8 rows x
// 128 contiguous B (16 full lines). K global->reg->FMA (no LDS round trip),
// 3-buffer rotation (2 row-groups in flight). q held in 16 float4 registers.
// Dot finished by shfl_xor over dg; sbuf feeds lane-owns-t softmax.
// PV: half-wave owns t-parity, dq owns d-quad, same 3-buffer prefetch.
// New token (t == start_pos) merged from RoPE'd k/v (cache not mutated).
// attn_part: [TSPLIT][32][8][4][130] = {m, l, o[128]}
// ---------------------------------------------------------------------------
__global__ __launch_bounds__(256, 2) void attn_kernel(
    const float* __restrict__ qkv,       // [32][6144]
    const float* __restrict__ cache_k,   // [32][2048][8][128]
    const float* __restrict__ cache_v,
    const int* __restrict__ spp,
    float* __restrict__ attn_part)
{
  __shared__ float sbuf[4][64][4];   // per-wave s (then p) per (t, head)
  __shared__ float kn_s[128], vn_s[128];
  __shared__ float comb[4][520];     // per-wave o[4][128] + m[4] + l[4]

  int bid = blockIdx.x;
  int ts = bid & (TSPLIT - 1), h = (bid >> 1) & 7, b = bid >> 4;
  int sp = *spp;                              // 2047
  const float scale = 0.088388347648318447f;  // 1/sqrt(128)
  int tid = threadIdx.x;

  if (tid < 128)      kn_s[tid]       = qkv[(size_t)b * 6144 + 4096 + h * 128 + tid];
  else                vn_s[tid - 128] = qkv[(size_t)b * 6144 + 5120 + h * 128 + tid - 128];
  __syncthreads();

  int wave = tid >> 6, lane = tid & 63;
  int half = lane >> 5, dq = lane & 31;       // PV decomposition
  int tl = lane & 7,  dg = lane >> 3;         // QK decomposition
  int base0 = ts * 1024 + wave * 256;
  const float* Kb = cache_k + (size_t)b * 2048 * 1024 + h * 128;
  const float* Vb = cache_v + (size_t)b * 2048 * 1024 + h * 128;

  // q -> registers: qreg[r][i] = q[head r][cols dg*4 + i*32 .. +3] (unscaled)
  float4 qreg[4][4];
  {
    const float* qb = qkv + (size_t)b * 6144 + h * 512;
    #pragma unroll
    for (int r = 0; r < 4; r++)
      #pragma unroll
      for (int i = 0; i < 4; i++)
        qreg[r][i] = *(const float4*)(qb + r * 128 + dg * 4 + i * 32);
  }

  float m[4]    = {-INFINITY, -INFINITY, -INFINITY, -INFINITY};
  float lsum[4] = {0.f, 0.f, 0.f, 0.f};
  float o[4][4] = {};

  for (int c = 0; c < 4; c++) {
    int tbase = base0 + c * 64;

    // ---- QK: 8 row-groups of 8 rows; 16 full 64B lines per instr ----
    {
      const float* Krow = Kb + (size_t)(tbase + tl) * 1024 + dg * 4;
      float4 kbuf[3][4];
      auto LOADG = [&](int g, int buf) {
        #pragma unroll
        for (int i = 0; i < 4; i++)
          kbuf[buf][i] = *(const float4*)(Krow + (size_t)g * 8192 + i * 32);
      };
      LOADG(0, 0); LOADG(1, 1);
      #pragma unroll
      for (int g = 0; g < 8; g++) {
        if (g + 2 < 8) LOADG(g + 2, (g + 2) % 3);
        const float4* kb = kbuf[g % 3];
        float sp4[4] = {0.f, 0.f, 0.f, 0.f};
        #pragma unroll
        for (int i = 0; i < 4; i++)
          #pragma unroll
          for (int r = 0; r < 4; r++)
            sp4[r] += kb[i].x * qreg[r][i].x + kb[i].y * qreg[r][i].y
                    + kb[i].z * qreg[r][i].z + kb[i].w * qreg[r][i].w;
        #pragma unroll
        for (int r = 0; r < 4; r++) {
          sp4[r] += __shfl_xor(sp4[r], 8);
          sp4[r] += __shfl_xor(sp4[r], 16);
          sp4[r] += __shfl_xor(sp4[r], 32);
        }
        if (dg == 0)
          *(float4*)(&sbuf[wave][g * 8 + tl][0]) = make_float4(
              sp4[0] * scale, sp4[1] * scale, sp4[2] * scale, sp4[3] * scale);
      }
    }

    // ---- softmax bookkeeping: lane owns t = tbase + lane ----
    {
      int t = tbase + lane;
      float4 sv = *(const float4*)(&sbuf[wave][lane][0]);
      float s4[4] = {sv.x, sv.y, sv.z, sv.w};
      if (t >= sp) { s4[0] = s4[1] = s4[2] = s4[3] = -INFINITY; }
      float pv[4];
      #pragma unroll
      for (int r = 0; r < 4; r++) {
        float cm = s4[r];
        #pragma unroll
        for (int off = 32; off >= 1; off >>= 1) cm = fmaxf(cm, __shfl_xor(cm, off));
        float nm = fmaxf(m[r], cm);
        float alpha, p;
        if (nm == -INFINITY) { alpha = 1.f; p = 0.f; }
        else {
          alpha = __expf(m[r] - nm);
          p = (s4[r] == -INFINITY) ? 0.f : __expf(s4[r] - nm);
        }
        m[r] = nm;
        lsum[r] = lsum[r] * alpha + p;
        #pragma unroll
        for (int j = 0; j < 4; j++) o[r][j] *= alpha;
        pv[r] = p;
      }
      *(float4*)(&sbuf[wave][lane][0]) = make_float4(pv[0], pv[1], pv[2], pv[3]);
    }

    // ---- PV: half-wave owns t-parity, dq owns d-quad; 2 rows/instr ----
    {
      const float* Vsrc = Vb + (size_t)(tbase + half) * 1024 + dq * 4;
      float4 vbuf[3][4];
      auto LOADV = [&](int G, int buf) {
        #pragma unroll
        for (int j = 0; j < 4; j++)
          vbuf[buf][j] = *(const float4*)(Vsrc + (size_t)(G * 8 + j * 2) * 1024);
      };
      LOADV(0, 0); LOADV(1, 1);
      #pragma unroll
      for (int G = 0; G < 8; G++) {
        if (G + 2 < 8) LOADV(G + 2, (G + 2) % 3);
        #pragma unroll
        for (int j = 0; j < 4; j++) {
          float4 vv = vbuf[G % 3][j];
          float4 pp = *(const float4*)(&sbuf[wave][G * 8 + j * 2 + half][0]);
          o[0][0] += pp.x * vv.x; o[0][1] += pp.x * vv.y;
          o[0][2] += pp.x * vv.z; o[0][3] += pp.x * vv.w;
          o[1][0] += pp.y * vv.x; o[1][1] += pp.y * vv.y;
          o[1][2] += pp.y * vv.z; o[1][3] += pp.y * vv.w;
          o[2][0] += pp.z * vv.x; o[2][1] += pp.z * vv.y;
          o[2][2] += pp.z * vv.z; o[2][3] += pp.z * vv.w;
          o[3][0] += pp.w * vv.x; o[3][1] += pp.w * vv.y;
          o[3][2] += pp.w * vv.z; o[3][3] += pp.w * vv.w;
        }
      }
    }
  }

  // merge the new token (position sp) from RoPE'd k/v in the owning block
  if (wave == 0 && sp >= ts * 1024 && sp < ts * 1024 + 1024) {
    float4 kn4[4];
    #pragma unroll
    for (int i = 0; i < 4; i++)
      kn4[i] = *(const float4*)(&kn_s[dg * 4 + i * 32]);
    float sNew[4];
    #pragma unroll
    for (int r = 0; r < 4; r++) {
      float a = 0.f;
      #pragma unroll
      for (int i = 0; i < 4; i++)
        a += kn4[i].x * qreg[r][i].x + kn4[i].y * qreg[r][i].y
           + kn4[i].z * qreg[r][i].z + kn4[i].w * qreg[r][i].w;
      a += __shfl_xor(a, 8);
      a += __shfl_xor(a, 16);
      a += __shfl_xor(a, 32);
      sNew[r] = a * scale;
    }
    #pragma unroll
    for (int r = 0; r < 4; r++) {
      float nm = fmaxf(m[r], sNew[r]);
      float alpha = (m[r] == -INFINITY) ? 0.f : __expf(m[r] - nm);
      float p = __expf(sNew[r] - nm);
      m[r] = nm;
      lsum[r] = lsum[r] * alpha + ((lane == 0) ? p : 0.f);
      float sel = (half == 0) ? p : 0.f;      // add new token once per d-quad
      #pragma unroll
      for (int j = 0; j < 4; j++)
        o[r][j] = o[r][j] * alpha + sel * vn_s[dq * 4 + j];
    }
  }

  // per-wave wrap-up: reduce l over lanes, sum o across halves, publish
  #pragma unroll
  for (int r = 0; r < 4; r++) {
    float L = lsum[r];
    #pragma unroll
    for (int off = 32; off >= 1; off >>= 1) L += __shfl_xor(L, off);
    #pragma unroll
    for (int j = 0; j < 4; j++) o[r][j] += __shfl_xor(o[r][j], 32);
    if (lane == 0) { comb[wave][512 + r] = m[r]; comb[wave][516 + r] = L; }
    if (half == 0) {
      #pragma unroll
      for (int j = 0; j < 4; j++) comb[wave][r * 128 + dq * 4 + j] = o[r][j];
    }
  }
  __syncthreads();
  // combine 4 waves; thread = (r, d-pair)
  {
    int r = tid >> 6, dp = tid & 63;
    float gm = fmaxf(fmaxf(comb[0][512 + r], comb[1][512 + r]),
                     fmaxf(comb[2][512 + r], comb[3][512 + r]));
    float L = 0.f, O0 = 0.f, O1 = 0.f;
    #pragma unroll
    for (int wv = 0; wv < 4; wv++) {
      float mm = comb[wv][512 + r];
      float al = (mm == -INFINITY) ? 0.f : __expf(mm - gm);
      L  += comb[wv][516 + r] * al;
      O0 += comb[wv][r * 128 + dp * 2]     * al;
      O1 += comb[wv][r * 128 + dp * 2 + 1] * al;
    }
    float* ap = attn_part + ((((size_t)ts * 32 + b) * 8 + h) * 4 + r) * 130;
    if (dp == 0) { ap[0] = gm; ap[1] = L; }
    ap[2 + dp * 2] = O0;
    ap[3 + dp * 2] = O1;
  }
}

// ---------------------------------------------------------------------------
// Combine the TSPLIT t-split partials and divide by l.
// ---------------------------------------------------------------------------
__global__ __launch_bounds__(256) void attn_combine_kernel(
    const float* __restrict__ attn_part, float* __restrict__ attn)
{
  int idx = blockIdx.x * 256 + threadIdx.x;   // 131072 = 32*8*4*128
  int d = idx & 127;
  int r = (idx >> 7) & 3;
  int h = (idx >> 9) & 7;
  int b = idx >> 12;
  float mv[TSPLIT], lv[TSPLIT], ov[TSPLIT];
  float gm = -INFINITY;
  #pragma unroll
  for (int ts = 0; ts < TSPLIT; ts++) {
    const float* ap = attn_part + (((size_t)(ts * 32 + b) * 8 + h) * 4 + r) * 130;
    mv[ts] = ap[0]; lv[ts] = ap[1]; ov[ts] = ap[2 + d];
    gm = fmaxf(gm, mv[ts]);
  }
  float L = 0.f, O = 0.f;
  #pragma unroll
  for (int ts = 0; ts < TSPLIT; ts++) {
    float al = (mv[ts] == -INFINITY) ? 0.f : __expf(mv[ts] - gm);
    L += lv[ts] * al;
    O += ov[ts] * al;
  }
  attn[idx] = O / L;                          // idx == b*4096 + (h*4+r)*128 + d
}

extern "C" void kernel_launch(void* const* d_in, const int* in_sizes, int n_in,
                              void* d_out, int out_size, void* d_ws, size_t ws_size,
                              hipStream_t stream)
{
  const float* x   = (const float*)d_in[0];
  const float* wq  = (const float*)d_in[1];
  const float* wk  = (const float*)d_in[2];
  const float* wv  = (const float*)d_in[3];
  const float* wo  = (const float*)d_in[4];
  const float* fc  = (const float*)d_in[5];
  const float* fs  = (const float*)d_in[6];
  const float* ck  = (const float*)d_in[7];
  const float* cv  = (const float*)d_in[8];
  const int*   spp = (const int*)d_in[9];
  float* out = (float*)d_out;

  float* ws = (float*)d_ws;
  float* qkv_part  = ws;                    // [16][32][6144] = 3145728 f
  float* out_part  = ws;                    // alias: disjoint lifetime
  float* qkvbuf    = ws + 3145728;          // [32][6144]     = 196608 f
  float* attn_part = qkvbuf + 196608;       // [2][32][8][4][130] = 266240 f
  float* attnbuf   = attn_part + 266240;    // [32][4096]     = 131072 f

  // QKV projections (fused, split-K)
  gemv_part_kernel<<<dim3(48, KSPLIT), 256, 0, stream>>>(
      x, wq, wk, wv, 32, 40, 0, 4096, 5120, 6144, qkv_part);
  // reduce + RoPE (q and k rotated, v passthrough)
  reduce_rope_kernel<<<384, 256, 0, stream>>>(qkv_part, 6144, fc, fs, 5120, qkvbuf);
  // attention over KV cache + new token
  attn_kernel<<<512, 256, 0, stream>>>(qkvbuf, ck, cv, spp, attn_part);
  attn_combine_kernel<<<512, 256, 0, stream>>>(attn_part, attnbuf);
  // output projection (split-K)
  gemv_part_kernel<<<dim3(32, KSPLIT), 256, 0, stream>>>(
      attnbuf, wo, wo, wo, 32, 32, 0, 0, 0, 4096, out_part);
  reduce_rope_kernel<<<256, 256, 0, stream>>>(out_part, 4096, fc, fs, 0, out);
}